// Round 1
// 546.572 us; speedup vs baseline: 1.0979x; 1.0979x over previous
//
#include <hip/hip_runtime.h>
#include <math.h>

#define N_NODES 20000
#define N_EDGES 640000
#define D 128      // NODE_DIM == HID
#define ED 64      // EDGE_DIM
#define EPS 1e-8f
#define MT 64      // rows per block in node_kernel
#define EMT 128    // edges per block in edge_kernel (2 M-tiles per wave)

#define RSTRIDE 136              // shared region row stride (bf16): 128 + 8 pad
#define HSTRIDE 136              // node kernel h1 stride
#define NSTRIDE 264              // node featA row stride: 256 + 8 pad

// d_ws layout (shorts unless noted):
//   eW1f @ 0 (80 frags) | eW2f @ 40960 | cW1f @ 57344 | nW1f @ 65536
//   nW2f @ 98304 | nfbf @ 114688 (2.56M shorts)
//   then i32: cnt @ short-ofs 2674688 (20000), cursor (+20000), perm (640000)
//   total 8,069,376 B  (ws_size proven >= 10.24 MB)
#define EW2_OFF 40960
#define CW1_OFF 57344
#define NW1_OFF 65536
#define NW2_OFF 98304
#define NFBF_OFF 114688
#define CSR_OFF  2674688   // in shorts; 4-byte aligned

typedef __attribute__((ext_vector_type(8))) short bf16x8;
typedef __attribute__((ext_vector_type(4))) short bf16x4;
typedef __attribute__((ext_vector_type(16))) float f32x16;

__device__ __forceinline__ float silu_f(float x) {
    return __fdividef(x, 1.0f + __expf(-x));
}

__device__ __forceinline__ short f2bf(float f) {   // RNE f32 -> bf16
    union { float f; unsigned u; } v; v.f = f;
    unsigned r = v.u + 0x7FFFu + ((v.u >> 16) & 1u);
    return (short)(r >> 16);
}
__device__ __forceinline__ float bf2f(short s) {
    union { unsigned u; float f; } v;
    v.u = ((unsigned)(unsigned short)s) << 16;
    return v.f;
}

#define SWZ_ADD(x, imm) (x + __int_as_float( \
    __builtin_amdgcn_ds_swizzle(__float_as_int(x), imm)))

// ---------------------------------------------------------------------------
// prep: weights -> 32x32x16 B-frag order; node_feat -> bf16; zero aggr; zero
// CSR counters; seed out_coords = coords.
// ---------------------------------------------------------------------------
__global__ __launch_bounds__(256)
void prep_kernel(const float* __restrict__ eW1, const float* __restrict__ eW2,
                 const float* __restrict__ cW1, const float* __restrict__ nW1,
                 const float* __restrict__ nW2,
                 const float* __restrict__ node_feat,
                 const float* __restrict__ coords,
                 short* __restrict__ wsf, short* __restrict__ nfbf,
                 int* __restrict__ cnt,
                 float* __restrict__ nodes_io, float* __restrict__ out_coords) {
    const int t = blockIdx.x * blockDim.x + threadIdx.x;
    const int nthr = gridDim.x * blockDim.x;

    if (t < 224 * 64) {
        int f = t >> 6, lane = t & 63;
        const float* src; int kc, nt, ncol; size_t dst;
        if (f < 80)       {              src = eW1; kc = f >> 2;  nt = f & 3;  ncol = 128; dst = (size_t)f * 512; }
        else if (f < 112) { int g=f-80;  src = eW2; kc = g >> 2;  nt = g & 3;  ncol = 128; dst = EW2_OFF + (size_t)g * 512; }
        else if (f < 128) { int g=f-112; src = cW1; kc = g >> 1;  nt = g & 1;  ncol = 64;  dst = CW1_OFF + (size_t)g * 512; }
        else if (f < 192) { int g=f-128; src = nW1; kc = g >> 2;  nt = g & 3;  ncol = 128; dst = NW1_OFF + (size_t)g * 512; }
        else              { int g=f-192; src = nW2; kc = g >> 2;  nt = g & 3;  ncol = 128; dst = NW2_OFF + (size_t)g * 512; }
        int col = nt * 32 + (lane & 31);
        int k0  = kc * 16 + (lane >> 5) * 8;
        bf16x8 o;
        #pragma unroll
        for (int j = 0; j < 8; ++j) o[j] = f2bf(src[(size_t)(k0 + j) * ncol + col]);
        *(bf16x8*)&wsf[dst + (size_t)lane * 8] = o;
    }
    for (int idx = t; idx < N_NODES * D / 8; idx += nthr) {
        const float* s = node_feat + (size_t)idx * 8;
        float4 f0 = *(const float4*)s, f1 = *(const float4*)(s + 4);
        bf16x8 pk;
        pk[0]=f2bf(f0.x); pk[1]=f2bf(f0.y); pk[2]=f2bf(f0.z); pk[3]=f2bf(f0.w);
        pk[4]=f2bf(f1.x); pk[5]=f2bf(f1.y); pk[6]=f2bf(f1.z); pk[7]=f2bf(f1.w);
        *(bf16x8*)&nfbf[(size_t)idx * 8] = pk;
    }
    for (int idx = t; idx < N_NODES * D / 4; idx += nthr) {
        float4 z; z.x = 0.f; z.y = 0.f; z.z = 0.f; z.w = 0.f;
        *(float4*)&nodes_io[(size_t)idx * 4] = z;
    }
    for (int idx = t; idx < N_NODES; idx += nthr) cnt[idx] = 0;
    for (int idx = t; idx < N_NODES * 3; idx += nthr)
        out_coords[idx] = coords[idx];
}

// ---------------------------------------------------------------------------
// CSR build: histogram -> exclusive scan (LDS-staged, coalesced) -> scatter.
// ---------------------------------------------------------------------------
__global__ __launch_bounds__(256)
void hist_kernel(const int* __restrict__ edge_index, int* __restrict__ cnt) {
    int t = blockIdx.x * blockDim.x + threadIdx.x;
    if (t < N_EDGES) atomicAdd(&cnt[edge_index[N_EDGES + t]], 1);
}

#define SCAN_T 1024
#define SCAN_C 20
__global__ __launch_bounds__(SCAN_T)
void scan_kernel(const int* __restrict__ cnt, int* __restrict__ cursor) {
    __shared__ int lc[N_NODES];      // 80 KB, single block
    __shared__ int part[SCAN_T];
    const int t = threadIdx.x;
    for (int i = t * 4; i < N_NODES; i += SCAN_T * 4)
        *(int4*)&lc[i] = *(const int4*)&cnt[i];
    __syncthreads();
    const int base = t * SCAN_C;
    int s = 0;
    #pragma unroll
    for (int i = 0; i < SCAN_C; ++i) {
        int idx = base + i;
        if (idx < N_NODES) s += lc[idx];
    }
    part[t] = s;
    __syncthreads();
    for (int off = 1; off < SCAN_T; off <<= 1) {
        int v = (t >= off) ? part[t - off] : 0;
        __syncthreads();
        part[t] += v;
        __syncthreads();
    }
    int run = part[t] - s;   // exclusive prefix of this thread's chunk
    #pragma unroll
    for (int i = 0; i < SCAN_C; ++i) {
        int idx = base + i;
        if (idx < N_NODES) { int c = lc[idx]; lc[idx] = run; run += c; }
    }
    __syncthreads();
    for (int i = t * 4; i < N_NODES; i += SCAN_T * 4)
        *(int4*)&cursor[i] = *(const int4*)&lc[i];
}

__global__ __launch_bounds__(256)
void scatter_kernel(const int* __restrict__ edge_index,
                    int* __restrict__ cursor, int* __restrict__ perm) {
    int t = blockIdx.x * blockDim.x + threadIdx.x;
    if (t < N_EDGES) {
        int d = edge_index[N_EDGES + t];
        int pos = atomicAdd(&cursor[d], 1);
        perm[pos] = t;
    }
}

// ---------------------------------------------------------------------------
// edge kernel: 128 dst-sorted edges/block, 256 threads / 4 waves.
// Register blocking: each wave owns TWO 32-row M-tiles x one 64-col half
// (4 f32x16 accumulators). Per kc step 2 b-frags feed 4 MFMA -> halves
// per-edge W L2 traffic, halves barrier count per edge, doubles MFMA ILP.
// LDS ~38 KB -> 4 blocks/CU (16 waves, launch_bounds(256,4) caps 128 regs).
// ---------------------------------------------------------------------------
__global__ __launch_bounds__(256, 4)
void edge_kernel(const short* __restrict__ nfbf,
                 const int* __restrict__ edge_index,
                 const int* __restrict__ perm,
                 const float* __restrict__ edge_attr,
                 const float* __restrict__ coords,
                 const float* __restrict__ eb1, const float* __restrict__ eb2,
                 const float* __restrict__ cb1, const float* __restrict__ cW2,
                 const float* __restrict__ cb2,
                 const short* __restrict__ wsf,
                 float* __restrict__ aggr_nodes, float* __restrict__ out_coords) {
    __shared__ __align__(16) short R[EMT * RSTRIDE];   // 34816 B
    __shared__ int s_src[EMT], s_dst[EMT];
    __shared__ float s_wgt[EMT];
    __shared__ float s_cv[EMT][3];
    __shared__ char s_segend[EMT];

    const int tid = threadIdx.x;
    const int E0 = blockIdx.x * EMT;

    const int ie = tid >> 1, p = tid & 1;       // 2 threads/edge
    const int eid  = perm[E0 + ie];
    const int esrc = edge_index[eid];
    const int edst = edge_index[N_EDGES + eid];
    if (p == 0) { s_src[ie] = esrc; s_dst[ie] = edst; }
    if (tid < EMT) s_wgt[tid] = 0.0f;

    // ---- stage chunk 0: src rows (each thread: contiguous 128 B half-row) ----
    {
        const short* row = nfbf + (size_t)esrc * D + p * 64;
        short* dstp = &R[ie * RSTRIDE + p * 64];
        #pragma unroll
        for (int c = 0; c < 8; ++c)
            *(bf16x8*)&dstp[c * 8] = *(const bf16x8*)&row[c * 8];
    }
    __syncthreads();                                           // B1
    if (tid < EMT)
        s_segend[tid] = (tid == EMT - 1) || (s_dst[tid] != s_dst[tid + 1]);

    const int lane  = tid & 63;
    const int wv    = tid >> 6;          // 0..3
    const int n0q   = wv & 1;            // column half
    const int m0a   = (wv >> 1) * 64;    // first M-tile
    const int m0b   = m0a + 32;          // second M-tile
    const int l31   = lane & 31;
    const int khalf = lane >> 5;

    const bf16x8* W1 = (const bf16x8*)wsf;
    const bf16x8* W2 = (const bf16x8*)(wsf + EW2_OFF);
    const bf16x8* W3 = (const bf16x8*)(wsf + CW1_OFF);

    f32x16 acc00, acc01, acc10, acc11;
    #pragma unroll
    for (int r = 0; r < 16; ++r) { acc00[r]=0.f; acc01[r]=0.f; acc10[r]=0.f; acc11[r]=0.f; }

    // ---- GEMM1a: kc 0..7 (src cols) ----
    #pragma unroll
    for (int kcl = 0; kcl < 8; ++kcl) {
        bf16x8 a0 = *(const bf16x8*)&R[(m0a + l31) * RSTRIDE + kcl * 16 + khalf * 8];
        bf16x8 a1 = *(const bf16x8*)&R[(m0b + l31) * RSTRIDE + kcl * 16 + khalf * 8];
        bf16x8 b0 = W1[((kcl) * 4 + n0q * 2 + 0) * 64 + lane];
        bf16x8 b1 = W1[((kcl) * 4 + n0q * 2 + 1) * 64 + lane];
        acc00 = __builtin_amdgcn_mfma_f32_32x32x16_bf16(a0, b0, acc00, 0, 0, 0);
        acc01 = __builtin_amdgcn_mfma_f32_32x32x16_bf16(a0, b1, acc01, 0, 0, 0);
        acc10 = __builtin_amdgcn_mfma_f32_32x32x16_bf16(a1, b0, acc10, 0, 0, 0);
        acc11 = __builtin_amdgcn_mfma_f32_32x32x16_bf16(a1, b1, acc11, 0, 0, 0);
    }
    __syncthreads();                                           // B2

    // ---- stage chunk 1: dst rows ----
    {
        const short* row = nfbf + (size_t)edst * D + p * 64;
        short* dstp = &R[ie * RSTRIDE + p * 64];
        #pragma unroll
        for (int c = 0; c < 8; ++c)
            *(bf16x8*)&dstp[c * 8] = *(const bf16x8*)&row[c * 8];
    }
    __syncthreads();                                           // B3

    // ---- GEMM1b: kc 8..15 (dst cols) ----
    #pragma unroll
    for (int kcl = 0; kcl < 8; ++kcl) {
        bf16x8 a0 = *(const bf16x8*)&R[(m0a + l31) * RSTRIDE + kcl * 16 + khalf * 8];
        bf16x8 a1 = *(const bf16x8*)&R[(m0b + l31) * RSTRIDE + kcl * 16 + khalf * 8];
        bf16x8 b0 = W1[((8 + kcl) * 4 + n0q * 2 + 0) * 64 + lane];
        bf16x8 b1 = W1[((8 + kcl) * 4 + n0q * 2 + 1) * 64 + lane];
        acc00 = __builtin_amdgcn_mfma_f32_32x32x16_bf16(a0, b0, acc00, 0, 0, 0);
        acc01 = __builtin_amdgcn_mfma_f32_32x32x16_bf16(a0, b1, acc01, 0, 0, 0);
        acc10 = __builtin_amdgcn_mfma_f32_32x32x16_bf16(a1, b0, acc10, 0, 0, 0);
        acc11 = __builtin_amdgcn_mfma_f32_32x32x16_bf16(a1, b1, acc11, 0, 0, 0);
    }
    __syncthreads();                                           // B4

    // ---- stage chunk 2: edge_attr (64 cols, f32->bf16; 32 floats/thread) ----
    {
        const float* arow = edge_attr + (size_t)eid * ED + p * 32;
        #pragma unroll
        for (int c = 0; c < 2; ++c) {
            float4 a0 = *(const float4*)&arow[c * 16 + 0];
            float4 a1 = *(const float4*)&arow[c * 16 + 4];
            float4 a2 = *(const float4*)&arow[c * 16 + 8];
            float4 a3 = *(const float4*)&arow[c * 16 + 12];
            bf16x8 p0, p1;
            p0[0]=f2bf(a0.x); p0[1]=f2bf(a0.y); p0[2]=f2bf(a0.z); p0[3]=f2bf(a0.w);
            p0[4]=f2bf(a1.x); p0[5]=f2bf(a1.y); p0[6]=f2bf(a1.z); p0[7]=f2bf(a1.w);
            p1[0]=f2bf(a2.x); p1[1]=f2bf(a2.y); p1[2]=f2bf(a2.z); p1[3]=f2bf(a2.w);
            p1[4]=f2bf(a3.x); p1[5]=f2bf(a3.y); p1[6]=f2bf(a3.z); p1[7]=f2bf(a3.w);
            *(bf16x8*)&R[ie * RSTRIDE + p * 32 + c * 16]     = p0;
            *(bf16x8*)&R[ie * RSTRIDE + p * 32 + c * 16 + 8] = p1;
        }
    }
    __syncthreads();                                           // B5

    // ---- GEMM1c: kc 16..19 (ea cols) ----
    #pragma unroll
    for (int kcl = 0; kcl < 4; ++kcl) {
        bf16x8 a0 = *(const bf16x8*)&R[(m0a + l31) * RSTRIDE + kcl * 16 + khalf * 8];
        bf16x8 a1 = *(const bf16x8*)&R[(m0b + l31) * RSTRIDE + kcl * 16 + khalf * 8];
        bf16x8 b0 = W1[((16 + kcl) * 4 + n0q * 2 + 0) * 64 + lane];
        bf16x8 b1 = W1[((16 + kcl) * 4 + n0q * 2 + 1) * 64 + lane];
        acc00 = __builtin_amdgcn_mfma_f32_32x32x16_bf16(a0, b0, acc00, 0, 0, 0);
        acc01 = __builtin_amdgcn_mfma_f32_32x32x16_bf16(a0, b1, acc01, 0, 0, 0);
        acc10 = __builtin_amdgcn_mfma_f32_32x32x16_bf16(a1, b0, acc10, 0, 0, 0);
        acc11 = __builtin_amdgcn_mfma_f32_32x32x16_bf16(a1, b1, acc11, 0, 0, 0);
    }
    __syncthreads();                                           // B6

    // ---- h1 epilogue -> R ----
    #pragma unroll
    for (int mt = 0; mt < 2; ++mt) {
        int m0 = mt ? m0b : m0a;
        #pragma unroll
        for (int nt = 0; nt < 2; ++nt) {
            f32x16 A = mt ? (nt ? acc11 : acc10) : (nt ? acc01 : acc00);
            int n = n0q * 64 + nt * 32 + l31;
            float bb = eb1[n];
            #pragma unroll
            for (int r = 0; r < 16; ++r) {
                int row = (r & 3) + 8 * (r >> 2) + 4 * khalf;
                R[(m0 + row) * RSTRIDE + n] = f2bf(silu_f(A[r] + bb));
            }
        }
    }
    __syncthreads();                                           // B7

    // ---- GEMM2: msg = silu(h1 @ eW2 + eb2), K=128 ----
    #pragma unroll
    for (int r = 0; r < 16; ++r) { acc00[r]=0.f; acc01[r]=0.f; acc10[r]=0.f; acc11[r]=0.f; }
    #pragma unroll
    for (int kc = 0; kc < 8; ++kc) {
        bf16x8 a0 = *(const bf16x8*)&R[(m0a + l31) * RSTRIDE + kc * 16 + khalf * 8];
        bf16x8 a1 = *(const bf16x8*)&R[(m0b + l31) * RSTRIDE + kc * 16 + khalf * 8];
        bf16x8 b0 = W2[(kc * 4 + n0q * 2 + 0) * 64 + lane];
        bf16x8 b1 = W2[(kc * 4 + n0q * 2 + 1) * 64 + lane];
        acc00 = __builtin_amdgcn_mfma_f32_32x32x16_bf16(a0, b0, acc00, 0, 0, 0);
        acc01 = __builtin_amdgcn_mfma_f32_32x32x16_bf16(a0, b1, acc01, 0, 0, 0);
        acc10 = __builtin_amdgcn_mfma_f32_32x32x16_bf16(a1, b0, acc10, 0, 0, 0);
        acc11 = __builtin_amdgcn_mfma_f32_32x32x16_bf16(a1, b1, acc11, 0, 0, 0);
    }
    __syncthreads();                                           // B8 (h1 dead)

    // ---- msg epilogue -> R ----
    #pragma unroll
    for (int mt = 0; mt < 2; ++mt) {
        int m0 = mt ? m0b : m0a;
        #pragma unroll
        for (int nt = 0; nt < 2; ++nt) {
            f32x16 A = mt ? (nt ? acc11 : acc10) : (nt ? acc01 : acc00);
            int n = n0q * 64 + nt * 32 + l31;
            float bb = eb2[n];
            #pragma unroll
            for (int r = 0; r < 16; ++r) {
                int row = (r & 3) + 8 * (r >> 2) + 4 * khalf;
                R[(m0 + row) * RSTRIDE + n] = f2bf(silu_f(A[r] + bb));
            }
        }
    }
    __syncthreads();                                           // B9

    // ---- GEMM3 (split): wave takes column half n0q for both its M-tiles;
    // partials merged via LDS float atomics. ----
    {
        f32x16 c0, c1;
        #pragma unroll
        for (int r = 0; r < 16; ++r) { c0[r] = 0.f; c1[r] = 0.f; }
        #pragma unroll
        for (int kc = 0; kc < 8; ++kc) {
            bf16x8 a0 = *(const bf16x8*)&R[(m0a + l31) * RSTRIDE + kc * 16 + khalf * 8];
            bf16x8 a1 = *(const bf16x8*)&R[(m0b + l31) * RSTRIDE + kc * 16 + khalf * 8];
            bf16x8 b  = W3[(kc * 2 + n0q) * 64 + lane];
            c0 = __builtin_amdgcn_mfma_f32_32x32x16_bf16(a0, b, c0, 0, 0, 0);
            c1 = __builtin_amdgcn_mfma_f32_32x32x16_bf16(a1, b, c1, 0, 0, 0);
        }
        int ncol = n0q * 32 + l31;
        float b1a = cb1[ncol];
        float w2a = cW2[ncol];
        float part[16];
        // M-tile a
        #pragma unroll
        for (int r = 0; r < 16; ++r)
            part[r] = silu_f(c0[r] + b1a) * w2a;
        #pragma unroll
        for (int r = 0; r < 16; ++r) {
            part[r] = SWZ_ADD(part[r], 0x041F);
            part[r] = SWZ_ADD(part[r], 0x081F);
            part[r] = SWZ_ADD(part[r], 0x101F);
            part[r] = SWZ_ADD(part[r], 0x201F);
            part[r] = SWZ_ADD(part[r], 0x401F);
        }
        if (l31 == 0) {
            #pragma unroll
            for (int r = 0; r < 16; ++r)
                atomicAdd(&s_wgt[m0a + (r & 3) + 8 * (r >> 2) + 4 * khalf], part[r]);
        }
        // M-tile b
        #pragma unroll
        for (int r = 0; r < 16; ++r)
            part[r] = silu_f(c1[r] + b1a) * w2a;
        #pragma unroll
        for (int r = 0; r < 16; ++r) {
            part[r] = SWZ_ADD(part[r], 0x041F);
            part[r] = SWZ_ADD(part[r], 0x081F);
            part[r] = SWZ_ADD(part[r], 0x101F);
            part[r] = SWZ_ADD(part[r], 0x201F);
            part[r] = SWZ_ADD(part[r], 0x401F);
        }
        if (l31 == 0) {
            #pragma unroll
            for (int r = 0; r < 16; ++r)
                atomicAdd(&s_wgt[m0b + (r & 3) + 8 * (r >> 2) + 4 * khalf], part[r]);
        }
    }
    __syncthreads();                                           // B10

    // ---- per-edge coord vector into LDS ----
    if (tid < EMT) {
        int e = tid;
        float wgt = s_wgt[e] + cb2[0];
        int s = s_src[e], d = s_dst[e];
        float dx = coords[s * 3 + 0] - coords[d * 3 + 0];
        float dy = coords[s * 3 + 1] - coords[d * 3 + 1];
        float dz = coords[s * 3 + 2] - coords[d * 3 + 2];
        float inv = __fdividef(wgt, sqrtf(dx * dx + dy * dy + dz * dz) + EPS);
        s_cv[e][0] = dx * inv; s_cv[e][1] = dy * inv; s_cv[e][2] = dz * inv;
    }
    __syncthreads();                                           // B11

    // ---- message segment-reduction: thread = (column quad, 16-row stripe) ----
    {
        int q  = tid & 31;        // cols q*4 .. q*4+3
        int st = tid >> 5;        // rows st*16 .. st*16+15
        int cc = q * 4;
        float a0 = 0.f, a1 = 0.f, a2 = 0.f, a3 = 0.f;
        #pragma unroll
        for (int r = 0; r < 16; ++r) {
            int e = st * 16 + r;
            bf16x4 m = *(const bf16x4*)&R[e * RSTRIDE + cc];
            a0 += bf2f(m[0]); a1 += bf2f(m[1]); a2 += bf2f(m[2]); a3 += bf2f(m[3]);
            if (s_segend[e]) {
                float* ap = &aggr_nodes[(size_t)s_dst[e] * D + cc];
                unsafeAtomicAdd(ap + 0, a0); unsafeAtomicAdd(ap + 1, a1);
                unsafeAtomicAdd(ap + 2, a2); unsafeAtomicAdd(ap + 3, a3);
                a0 = a1 = a2 = a3 = 0.f;
            }
        }
        int elast = st * 16 + 15;
        if (!s_segend[elast]) {
            float* ap = &aggr_nodes[(size_t)s_dst[elast] * D + cc];
            unsafeAtomicAdd(ap + 0, a0); unsafeAtomicAdd(ap + 1, a1);
            unsafeAtomicAdd(ap + 2, a2); unsafeAtomicAdd(ap + 3, a3);
        }
    }

    // ---- coord segment-reduction: segment heads walk their run ----
    if (tid < EMT) {
        int e = tid;
        bool head = (e == 0) || (s_dst[e] != s_dst[e - 1]);
        if (head) {
            float sx = 0.f, sy = 0.f, sz = 0.f;
            int j = e;
            do {
                sx += s_cv[j][0]; sy += s_cv[j][1]; sz += s_cv[j][2];
                ++j;
            } while (j < EMT && s_dst[j] == s_dst[e]);
            int d = s_dst[e];
            unsafeAtomicAdd(&out_coords[d * 3 + 0], sx);
            unsafeAtomicAdd(&out_coords[d * 3 + 1], sy);
            unsafeAtomicAdd(&out_coords[d * 3 + 2], sz);
        }
    }
}

// ---------------------------------------------------------------------------
// node kernel (MFMA): 64 nodes/block; in-place aggr -> output.
// ---------------------------------------------------------------------------
__global__ __launch_bounds__(256, 4)
void node_kernel(const float* __restrict__ node_feat,
                 const short* __restrict__ nfbf,
                 float* nodes_io,
                 const float* __restrict__ nb1, const float* __restrict__ nb2,
                 const short* __restrict__ wsf) {
    __shared__ __align__(16) short lds[MT * NSTRIDE];
    const int tid = threadIdx.x;
    const int N0 = blockIdx.x * MT;

    {
        int i = tid >> 2, p = tid & 3;
        int nid = N0 + i; if (nid > N_NODES - 1) nid = N_NODES - 1;
        const short* frow = nfbf + (size_t)nid * D;
        short* drow = &lds[i * NSTRIDE];
        #pragma unroll
        for (int c = 0; c < 4; ++c)
            *(bf16x8*)&drow[c * 32 + p * 8] = *(const bf16x8*)&frow[c * 32 + p * 8];
        const float* arow = nodes_io + (size_t)nid * D + p * 32;
        #pragma unroll
        for (int c = 0; c < 4; ++c) {
            float4 f0 = *(const float4*)&arow[c * 8];
            float4 f1 = *(const float4*)&arow[c * 8 + 4];
            bf16x8 pk;
            pk[0]=f2bf(f0.x); pk[1]=f2bf(f0.y); pk[2]=f2bf(f0.z); pk[3]=f2bf(f0.w);
            pk[4]=f2bf(f1.x); pk[5]=f2bf(f1.y); pk[6]=f2bf(f1.z); pk[7]=f2bf(f1.w);
            *(bf16x8*)&drow[128 + p * 32 + c * 8] = pk;
        }
    }
    __syncthreads();

    const int lane  = tid & 63;
    const int wv    = tid >> 6;
    const int m0    = (wv >> 1) * 32;
    const int n0q   = wv & 1;
    const int l31   = lane & 31;
    const int khalf = lane >> 5;

    const bf16x8* W1 = (const bf16x8*)(wsf + NW1_OFF);
    const bf16x8* W2 = (const bf16x8*)(wsf + NW2_OFF);

    {
        f32x16 acc0, acc1;
        #pragma unroll
        for (int r = 0; r < 16; ++r) { acc0[r] = 0.f; acc1[r] = 0.f; }
        #pragma unroll
        for (int kc = 0; kc < 16; ++kc) {
            bf16x8 a  = *(const bf16x8*)&lds[(m0 + l31) * NSTRIDE + kc * 16 + khalf * 8];
            bf16x8 b0 = W1[(kc * 4 + n0q * 2 + 0) * 64 + lane];
            bf16x8 b1 = W1[(kc * 4 + n0q * 2 + 1) * 64 + lane];
            acc0 = __builtin_amdgcn_mfma_f32_32x32x16_bf16(a, b0, acc0, 0, 0, 0);
            acc1 = __builtin_amdgcn_mfma_f32_32x32x16_bf16(a, b1, acc1, 0, 0, 0);
        }
        __syncthreads();
        #pragma unroll
        for (int nt = 0; nt < 2; ++nt) {
            f32x16 A = nt ? acc1 : acc0;
            int n = n0q * 64 + nt * 32 + l31;
            float bb = nb1[n];
            #pragma unroll
            for (int r = 0; r < 16; ++r) {
                int row = (r & 3) + 8 * (r >> 2) + 4 * khalf;
                lds[(m0 + row) * HSTRIDE + n] = f2bf(silu_f(A[r] + bb));
            }
        }
    }
    __syncthreads();

    {
        f32x16 acc0, acc1;
        #pragma unroll
        for (int r = 0; r < 16; ++r) { acc0[r] = 0.f; acc1[r] = 0.f; }
        #pragma unroll
        for (int kc = 0; kc < 8; ++kc) {
            bf16x8 a  = *(const bf16x8*)&lds[(m0 + l31) * HSTRIDE + kc * 16 + khalf * 8];
            bf16x8 b0 = W2[(kc * 4 + n0q * 2 + 0) * 64 + lane];
            bf16x8 b1 = W2[(kc * 4 + n0q * 2 + 1) * 64 + lane];
            acc0 = __builtin_amdgcn_mfma_f32_32x32x16_bf16(a, b0, acc0, 0, 0, 0);
            acc1 = __builtin_amdgcn_mfma_f32_32x32x16_bf16(a, b1, acc1, 0, 0, 0);
        }
        #pragma unroll
        for (int nt = 0; nt < 2; ++nt) {
            f32x16 A = nt ? acc1 : acc0;
            int n = n0q * 64 + nt * 32 + l31;
            float bb = nb2[n];
            #pragma unroll
            for (int r = 0; r < 16; ++r) {
                int row = (r & 3) + 8 * (r >> 2) + 4 * khalf;
                int nid = N0 + m0 + row;
                if (nid < N_NODES)
                    nodes_io[(size_t)nid * D + n] = A[r] + bb + node_feat[(size_t)nid * D + n];
            }
        }
    }
}

extern "C" void kernel_launch(void* const* d_in, const int* in_sizes, int n_in,
                              void* d_out, int out_size, void* d_ws, size_t ws_size,
                              hipStream_t stream) {
    const float* node_feat  = (const float*)d_in[0];
    const int*   edge_index = (const int*)d_in[1];
    const float* edge_attr  = (const float*)d_in[2];
    const float* coords     = (const float*)d_in[3];
    const float* eW1 = (const float*)d_in[4];
    const float* eb1 = (const float*)d_in[5];
    const float* eW2 = (const float*)d_in[6];
    const float* eb2 = (const float*)d_in[7];
    const float* nW1 = (const float*)d_in[8];
    const float* nb1 = (const float*)d_in[9];
    const float* nW2 = (const float*)d_in[10];
    const float* nb2 = (const float*)d_in[11];
    const float* cW1 = (const float*)d_in[12];
    const float* cb1 = (const float*)d_in[13];
    const float* cW2 = (const float*)d_in[14];
    const float* cb2 = (const float*)d_in[15];

    float* nodes_io   = (float*)d_out;                 // aggr, then node output
    float* out_coords = nodes_io + (size_t)N_NODES * D;
    short* wsf    = (short*)d_ws;
    short* nfbf   = wsf + NFBF_OFF;
    int*   cnt    = (int*)(wsf + CSR_OFF);
    int*   cursor = cnt + N_NODES;
    int*   perm   = cursor + N_NODES;

    prep_kernel<<<256, 256, 0, stream>>>(
        eW1, eW2, cW1, nW1, nW2, node_feat, coords,
        wsf, nfbf, cnt, nodes_io, out_coords);
    hist_kernel<<<N_EDGES / 256, 256, 0, stream>>>(edge_index, cnt);
    scan_kernel<<<1, SCAN_T, 0, stream>>>(cnt, cursor);
    scatter_kernel<<<N_EDGES / 256, 256, 0, stream>>>(edge_index, cursor, perm);
    edge_kernel<<<N_EDGES / EMT, 256, 0, stream>>>(
        nfbf, edge_index, perm, edge_attr, coords,
        eb1, eb2, cb1, cW2, cb2, wsf, nodes_io, out_coords);
    node_kernel<<<(N_NODES + MT - 1) / MT, 256, 0, stream>>>(
        node_feat, nfbf, nodes_io, nb1, nb2, wsf);
}

// Round 4
// 526.587 us; speedup vs baseline: 1.1396x; 1.0380x over previous
//
#include <hip/hip_runtime.h>
#include <math.h>

#define N_NODES 20000
#define N_EDGES 640000
#define D 128      // NODE_DIM == HID
#define ED 64      // EDGE_DIM
#define EPS 1e-8f
#define MT 64      // rows per block in node_kernel
#define EMT 128    // edges per block in edge_kernel (2 M-tiles per wave)

#define RSTRIDE 136              // shared region row stride (bf16): 128 + 8 pad
#define HSTRIDE 136              // node kernel h1 stride
#define NSTRIDE 264              // node featA row stride: 256 + 8 pad

// d_ws layout (shorts unless noted):
//   eW1f @ 0 (80 frags) | eW2f @ 40960 | cW1f @ 57344 | nW1f @ 65536
//   nW2f @ 98304 | nfbf @ 114688 (2.56M shorts)
//   then i32: cnt @ short-ofs 2674688 (20000), cursor (+20000), perm (640000)
#define EW2_OFF 40960
#define CW1_OFF 57344
#define NW1_OFF 65536
#define NW2_OFF 98304
#define NFBF_OFF 114688
#define CSR_OFF  2674688   // in shorts; 4-byte aligned

typedef __attribute__((ext_vector_type(8))) short bf16x8;
typedef __attribute__((ext_vector_type(4))) short bf16x4;
typedef __attribute__((ext_vector_type(16))) float f32x16;

__device__ __forceinline__ float silu_f(float x) {
    return __fdividef(x, 1.0f + __expf(-x));
}

__device__ __forceinline__ short f2bf(float f) {   // RNE f32 -> bf16
    union { float f; unsigned u; } v; v.f = f;
    unsigned r = v.u + 0x7FFFu + ((v.u >> 16) & 1u);
    return (short)(r >> 16);
}
__device__ __forceinline__ float bf2f(short s) {
    union { unsigned u; float f; } v;
    v.u = ((unsigned)(unsigned short)s) << 16;
    return v.f;
}
// HW packed f32x2 -> bf16x2 (RNE). dst.lo = cvt(lo), dst.hi = cvt(hi).
__device__ __forceinline__ unsigned cvt_pk_bf16(float lo, float hi) {
    unsigned r;
    asm("v_cvt_pk_bf16_f32 %0, %1, %2" : "=v"(r) : "v"(lo), "v"(hi));
    return r;
}

// ---------------------------------------------------------------------------
// prep: weights -> 32x32x16 B-frag order; node_feat -> bf16; zero aggr; zero
// CSR counters; seed out_coords = coords.
// ---------------------------------------------------------------------------
__global__ __launch_bounds__(256)
void prep_kernel(const float* __restrict__ eW1, const float* __restrict__ eW2,
                 const float* __restrict__ cW1, const float* __restrict__ nW1,
                 const float* __restrict__ nW2,
                 const float* __restrict__ node_feat,
                 const float* __restrict__ coords,
                 short* __restrict__ wsf, short* __restrict__ nfbf,
                 int* __restrict__ cnt,
                 float* __restrict__ nodes_io, float* __restrict__ out_coords) {
    const int t = blockIdx.x * blockDim.x + threadIdx.x;
    const int nthr = gridDim.x * blockDim.x;

    if (t < 224 * 64) {
        int f = t >> 6, lane = t & 63;
        const float* src; int kc, nt, ncol; size_t dst;
        if (f < 80)       {              src = eW1; kc = f >> 2;  nt = f & 3;  ncol = 128; dst = (size_t)f * 512; }
        else if (f < 112) { int g=f-80;  src = eW2; kc = g >> 2;  nt = g & 3;  ncol = 128; dst = EW2_OFF + (size_t)g * 512; }
        else if (f < 128) { int g=f-112; src = cW1; kc = g >> 1;  nt = g & 1;  ncol = 64;  dst = CW1_OFF + (size_t)g * 512; }
        else if (f < 192) { int g=f-128; src = nW1; kc = g >> 2;  nt = g & 3;  ncol = 128; dst = NW1_OFF + (size_t)g * 512; }
        else              { int g=f-192; src = nW2; kc = g >> 2;  nt = g & 3;  ncol = 128; dst = NW2_OFF + (size_t)g * 512; }
        int col = nt * 32 + (lane & 31);
        int k0  = kc * 16 + (lane >> 5) * 8;
        bf16x8 o;
        #pragma unroll
        for (int j = 0; j < 8; ++j) o[j] = f2bf(src[(size_t)(k0 + j) * ncol + col]);
        *(bf16x8*)&wsf[dst + (size_t)lane * 8] = o;
    }
    for (int idx = t; idx < N_NODES * D / 8; idx += nthr) {
        const float* s = node_feat + (size_t)idx * 8;
        float4 f0 = *(const float4*)s, f1 = *(const float4*)(s + 4);
        bf16x8 pk;
        pk[0]=f2bf(f0.x); pk[1]=f2bf(f0.y); pk[2]=f2bf(f0.z); pk[3]=f2bf(f0.w);
        pk[4]=f2bf(f1.x); pk[5]=f2bf(f1.y); pk[6]=f2bf(f1.z); pk[7]=f2bf(f1.w);
        *(bf16x8*)&nfbf[(size_t)idx * 8] = pk;
    }
    for (int idx = t; idx < N_NODES * D / 4; idx += nthr) {
        float4 z; z.x = 0.f; z.y = 0.f; z.z = 0.f; z.w = 0.f;
        *(float4*)&nodes_io[(size_t)idx * 4] = z;
    }
    for (int idx = t; idx < N_NODES; idx += nthr) cnt[idx] = 0;
    for (int idx = t; idx < N_NODES * 3; idx += nthr)
        out_coords[idx] = coords[idx];
}

// ---------------------------------------------------------------------------
// CSR build: histogram -> exclusive scan (LDS-staged, coalesced) -> scatter.
// ---------------------------------------------------------------------------
__global__ __launch_bounds__(256)
void hist_kernel(const int* __restrict__ edge_index, int* __restrict__ cnt) {
    int t = blockIdx.x * blockDim.x + threadIdx.x;
    if (t < N_EDGES) atomicAdd(&cnt[edge_index[N_EDGES + t]], 1);
}

#define SCAN_T 1024
#define SCAN_C 20
__global__ __launch_bounds__(SCAN_T)
void scan_kernel(const int* __restrict__ cnt, int* __restrict__ cursor) {
    __shared__ int lc[N_NODES];      // 80 KB, single block
    __shared__ int part[SCAN_T];
    const int t = threadIdx.x;
    for (int i = t * 4; i < N_NODES; i += SCAN_T * 4)
        *(int4*)&lc[i] = *(const int4*)&cnt[i];
    __syncthreads();
    const int base = t * SCAN_C;
    int s = 0;
    #pragma unroll
    for (int i = 0; i < SCAN_C; ++i) {
        int idx = base + i;
        if (idx < N_NODES) s += lc[idx];
    }
    part[t] = s;
    __syncthreads();
    for (int off = 1; off < SCAN_T; off <<= 1) {
        int v = (t >= off) ? part[t - off] : 0;
        __syncthreads();
        part[t] += v;
        __syncthreads();
    }
    int run = part[t] - s;   // exclusive prefix of this thread's chunk
    #pragma unroll
    for (int i = 0; i < SCAN_C; ++i) {
        int idx = base + i;
        if (idx < N_NODES) { int c = lc[idx]; lc[idx] = run; run += c; }
    }
    __syncthreads();
    for (int i = t * 4; i < N_NODES; i += SCAN_T * 4)
        *(int4*)&cursor[i] = *(const int4*)&lc[i];
}

__global__ __launch_bounds__(256)
void scatter_kernel(const int* __restrict__ edge_index,
                    int* __restrict__ cursor, int* __restrict__ perm) {
    int t = blockIdx.x * blockDim.x + threadIdx.x;
    if (t < N_EDGES) {
        int d = edge_index[N_EDGES + t];
        int pos = atomicAdd(&cursor[d], 1);
        perm[pos] = t;
    }
}

// ---------------------------------------------------------------------------
// edge kernel: 128 dst-sorted edges/block, 256 threads / 4 waves.
// MFMA operands SWAPPED (mfma(Wfrag, Xfrag)) -> D is transposed: each lane
// owns ONE edge row and 16 consecutive-in-n values (4 runs of 4). Epilogues
// pack 4 bf16 per ds_write_b64 (was 64 ds_write_b16), GEMM3 row-sum is
// lane-local (was 160 ds_swizzle/thread). Biases staged in LDS.
// ---------------------------------------------------------------------------
__global__ __launch_bounds__(256, 4)
void edge_kernel(const short* __restrict__ nfbf,
                 const int* __restrict__ edge_index,
                 const int* __restrict__ perm,
                 const float* __restrict__ edge_attr,
                 const float* __restrict__ coords,
                 const float* __restrict__ eb1, const float* __restrict__ eb2,
                 const float* __restrict__ cb1, const float* __restrict__ cW2,
                 const float* __restrict__ cb2,
                 const short* __restrict__ wsf,
                 float* __restrict__ aggr_nodes, float* __restrict__ out_coords) {
    __shared__ __align__(16) short R[EMT * RSTRIDE];   // 34816 B
    __shared__ int s_src[EMT], s_dst[EMT];
    __shared__ float s_wgt[EMT];
    __shared__ float s_cv[EMT][3];
    __shared__ char s_segend[EMT];
    __shared__ __align__(16) float s_eb1[D], s_eb2[D];
    __shared__ __align__(16) float s_cb1[ED], s_cw2[ED];

    const int tid = threadIdx.x;
    const int E0 = blockIdx.x * EMT;

    const int ie = tid >> 1, p = tid & 1;       // 2 threads/edge
    const int eid  = perm[E0 + ie];
    const int esrc = edge_index[eid];
    const int edst = edge_index[N_EDGES + eid];
    if (p == 0) { s_src[ie] = esrc; s_dst[ie] = edst; }
    if (tid < EMT) s_wgt[tid] = 0.0f;
    if (tid < 128) { s_eb1[tid] = eb1[tid]; s_eb2[tid] = eb2[tid]; }
    else if (tid < 192) { int i = tid - 128; s_cb1[i] = cb1[i]; s_cw2[i] = cW2[i]; }

    // ---- stage chunk 0: src rows (each thread: contiguous 128 B half-row) ----
    {
        const short* row = nfbf + (size_t)esrc * D + p * 64;
        short* dstp = &R[ie * RSTRIDE + p * 64];
        #pragma unroll
        for (int c = 0; c < 8; ++c)
            *(bf16x8*)&dstp[c * 8] = *(const bf16x8*)&row[c * 8];
    }
    __syncthreads();                                           // B1
    if (tid < EMT)
        s_segend[tid] = (tid == EMT - 1) || (s_dst[tid] != s_dst[tid + 1]);

    const int lane  = tid & 63;
    const int wv    = tid >> 6;          // 0..3
    const int n0q   = wv & 1;            // column half
    const int m0a   = (wv >> 1) * 64;    // first M-tile
    const int m0b   = m0a + 32;          // second M-tile
    const int l31   = lane & 31;
    const int khalf = lane >> 5;

    const bf16x8* W1 = (const bf16x8*)wsf;
    const bf16x8* W2 = (const bf16x8*)(wsf + EW2_OFF);
    const bf16x8* W3 = (const bf16x8*)(wsf + CW1_OFF);

    f32x16 acc00, acc01, acc10, acc11;
    #pragma unroll
    for (int r = 0; r < 16; ++r) { acc00[r]=0.f; acc01[r]=0.f; acc10[r]=0.f; acc11[r]=0.f; }

    // ---- GEMM1a: kc 0..7 (src cols) ----
    #pragma unroll
    for (int kcl = 0; kcl < 8; ++kcl) {
        bf16x8 a0 = *(const bf16x8*)&R[(m0a + l31) * RSTRIDE + kcl * 16 + khalf * 8];
        bf16x8 a1 = *(const bf16x8*)&R[(m0b + l31) * RSTRIDE + kcl * 16 + khalf * 8];
        bf16x8 b0 = W1[((kcl) * 4 + n0q * 2 + 0) * 64 + lane];
        bf16x8 b1 = W1[((kcl) * 4 + n0q * 2 + 1) * 64 + lane];
        acc00 = __builtin_amdgcn_mfma_f32_32x32x16_bf16(b0, a0, acc00, 0, 0, 0);
        acc01 = __builtin_amdgcn_mfma_f32_32x32x16_bf16(b1, a0, acc01, 0, 0, 0);
        acc10 = __builtin_amdgcn_mfma_f32_32x32x16_bf16(b0, a1, acc10, 0, 0, 0);
        acc11 = __builtin_amdgcn_mfma_f32_32x32x16_bf16(b1, a1, acc11, 0, 0, 0);
    }
    __syncthreads();                                           // B2

    // ---- stage chunk 1: dst rows ----
    {
        const short* row = nfbf + (size_t)edst * D + p * 64;
        short* dstp = &R[ie * RSTRIDE + p * 64];
        #pragma unroll
        for (int c = 0; c < 8; ++c)
            *(bf16x8*)&dstp[c * 8] = *(const bf16x8*)&row[c * 8];
    }
    __syncthreads();                                           // B3

    // ---- GEMM1b: kc 8..15 (dst cols) ----
    #pragma unroll
    for (int kcl = 0; kcl < 8; ++kcl) {
        bf16x8 a0 = *(const bf16x8*)&R[(m0a + l31) * RSTRIDE + kcl * 16 + khalf * 8];
        bf16x8 a1 = *(const bf16x8*)&R[(m0b + l31) * RSTRIDE + kcl * 16 + khalf * 8];
        bf16x8 b0 = W1[((8 + kcl) * 4 + n0q * 2 + 0) * 64 + lane];
        bf16x8 b1 = W1[((8 + kcl) * 4 + n0q * 2 + 1) * 64 + lane];
        acc00 = __builtin_amdgcn_mfma_f32_32x32x16_bf16(b0, a0, acc00, 0, 0, 0);
        acc01 = __builtin_amdgcn_mfma_f32_32x32x16_bf16(b1, a0, acc01, 0, 0, 0);
        acc10 = __builtin_amdgcn_mfma_f32_32x32x16_bf16(b0, a1, acc10, 0, 0, 0);
        acc11 = __builtin_amdgcn_mfma_f32_32x32x16_bf16(b1, a1, acc11, 0, 0, 0);
    }
    __syncthreads();                                           // B4

    // ---- stage chunk 2: edge_attr (64 cols, f32->bf16 via cvt_pk) ----
    {
        const float* arow = edge_attr + (size_t)eid * ED + p * 32;
        #pragma unroll
        for (int c = 0; c < 2; ++c) {
            float4 a0 = *(const float4*)&arow[c * 16 + 0];
            float4 a1 = *(const float4*)&arow[c * 16 + 4];
            float4 a2 = *(const float4*)&arow[c * 16 + 8];
            float4 a3 = *(const float4*)&arow[c * 16 + 12];
            uint4 q;
            q.x = cvt_pk_bf16(a0.x, a0.y); q.y = cvt_pk_bf16(a0.z, a0.w);
            q.z = cvt_pk_bf16(a1.x, a1.y); q.w = cvt_pk_bf16(a1.z, a1.w);
            *(uint4*)&R[ie * RSTRIDE + p * 32 + c * 16] = q;
            q.x = cvt_pk_bf16(a2.x, a2.y); q.y = cvt_pk_bf16(a2.z, a2.w);
            q.z = cvt_pk_bf16(a3.x, a3.y); q.w = cvt_pk_bf16(a3.z, a3.w);
            *(uint4*)&R[ie * RSTRIDE + p * 32 + c * 16 + 8] = q;
        }
    }
    __syncthreads();                                           // B5

    // ---- GEMM1c: kc 16..19 (ea cols) ----
    #pragma unroll
    for (int kcl = 0; kcl < 4; ++kcl) {
        bf16x8 a0 = *(const bf16x8*)&R[(m0a + l31) * RSTRIDE + kcl * 16 + khalf * 8];
        bf16x8 a1 = *(const bf16x8*)&R[(m0b + l31) * RSTRIDE + kcl * 16 + khalf * 8];
        bf16x8 b0 = W1[((16 + kcl) * 4 + n0q * 2 + 0) * 64 + lane];
        bf16x8 b1 = W1[((16 + kcl) * 4 + n0q * 2 + 1) * 64 + lane];
        acc00 = __builtin_amdgcn_mfma_f32_32x32x16_bf16(b0, a0, acc00, 0, 0, 0);
        acc01 = __builtin_amdgcn_mfma_f32_32x32x16_bf16(b1, a0, acc01, 0, 0, 0);
        acc10 = __builtin_amdgcn_mfma_f32_32x32x16_bf16(b0, a1, acc10, 0, 0, 0);
        acc11 = __builtin_amdgcn_mfma_f32_32x32x16_bf16(b1, a1, acc11, 0, 0, 0);
    }
    __syncthreads();                                           // B6

    // ---- h1 epilogue -> R: lane owns edge row, 4x packed b64 writes/acc ----
    #pragma unroll
    for (int mt = 0; mt < 2; ++mt) {
        int erow = (mt ? m0b : m0a) + l31;
        #pragma unroll
        for (int nt = 0; nt < 2; ++nt) {
            f32x16 A = mt ? (nt ? acc11 : acc10) : (nt ? acc01 : acc00);
            int base = n0q * 64 + nt * 32 + 4 * khalf;
            #pragma unroll
            for (int g = 0; g < 4; ++g) {
                int n = base + 8 * g;
                float4 b4 = *(const float4*)&s_eb1[n];
                uint2 dd;
                dd.x = cvt_pk_bf16(silu_f(A[4*g+0] + b4.x), silu_f(A[4*g+1] + b4.y));
                dd.y = cvt_pk_bf16(silu_f(A[4*g+2] + b4.z), silu_f(A[4*g+3] + b4.w));
                *(uint2*)&R[erow * RSTRIDE + n] = dd;
            }
        }
    }
    __syncthreads();                                           // B7

    // ---- GEMM2: msg = silu(h1 @ eW2 + eb2), K=128 ----
    #pragma unroll
    for (int r = 0; r < 16; ++r) { acc00[r]=0.f; acc01[r]=0.f; acc10[r]=0.f; acc11[r]=0.f; }
    #pragma unroll
    for (int kc = 0; kc < 8; ++kc) {
        bf16x8 a0 = *(const bf16x8*)&R[(m0a + l31) * RSTRIDE + kc * 16 + khalf * 8];
        bf16x8 a1 = *(const bf16x8*)&R[(m0b + l31) * RSTRIDE + kc * 16 + khalf * 8];
        bf16x8 b0 = W2[(kc * 4 + n0q * 2 + 0) * 64 + lane];
        bf16x8 b1 = W2[(kc * 4 + n0q * 2 + 1) * 64 + lane];
        acc00 = __builtin_amdgcn_mfma_f32_32x32x16_bf16(b0, a0, acc00, 0, 0, 0);
        acc01 = __builtin_amdgcn_mfma_f32_32x32x16_bf16(b1, a0, acc01, 0, 0, 0);
        acc10 = __builtin_amdgcn_mfma_f32_32x32x16_bf16(b0, a1, acc10, 0, 0, 0);
        acc11 = __builtin_amdgcn_mfma_f32_32x32x16_bf16(b1, a1, acc11, 0, 0, 0);
    }
    __syncthreads();                                           // B8 (h1 dead)

    // ---- msg epilogue -> R ----
    #pragma unroll
    for (int mt = 0; mt < 2; ++mt) {
        int erow = (mt ? m0b : m0a) + l31;
        #pragma unroll
        for (int nt = 0; nt < 2; ++nt) {
            f32x16 A = mt ? (nt ? acc11 : acc10) : (nt ? acc01 : acc00);
            int base = n0q * 64 + nt * 32 + 4 * khalf;
            #pragma unroll
            for (int g = 0; g < 4; ++g) {
                int n = base + 8 * g;
                float4 b4 = *(const float4*)&s_eb2[n];
                uint2 dd;
                dd.x = cvt_pk_bf16(silu_f(A[4*g+0] + b4.x), silu_f(A[4*g+1] + b4.y));
                dd.y = cvt_pk_bf16(silu_f(A[4*g+2] + b4.z), silu_f(A[4*g+3] + b4.w));
                *(uint2*)&R[erow * RSTRIDE + n] = dd;
            }
        }
    }
    __syncthreads();                                           // B9

    // ---- GEMM3: c = silu(msg@cW1+cb1)*cW2 summed over cols -> per-edge wgt.
    // Transposed D makes the row-sum lane-local: 16 local + shfl_xor(32). ----
    {
        f32x16 c0, c1;
        #pragma unroll
        for (int r = 0; r < 16; ++r) { c0[r] = 0.f; c1[r] = 0.f; }
        #pragma unroll
        for (int kc = 0; kc < 8; ++kc) {
            bf16x8 a0 = *(const bf16x8*)&R[(m0a + l31) * RSTRIDE + kc * 16 + khalf * 8];
            bf16x8 a1 = *(const bf16x8*)&R[(m0b + l31) * RSTRIDE + kc * 16 + khalf * 8];
            bf16x8 b  = W3[(kc * 2 + n0q) * 64 + lane];
            c0 = __builtin_amdgcn_mfma_f32_32x32x16_bf16(b, a0, c0, 0, 0, 0);
            c1 = __builtin_amdgcn_mfma_f32_32x32x16_bf16(b, a1, c1, 0, 0, 0);
        }
        float s0 = 0.f, s1 = 0.f;
        int nb = n0q * 32 + 4 * khalf;
        #pragma unroll
        for (int g = 0; g < 4; ++g) {
            float4 b4 = *(const float4*)&s_cb1[nb + 8 * g];
            float4 w4 = *(const float4*)&s_cw2[nb + 8 * g];
            s0 += silu_f(c0[4*g+0] + b4.x) * w4.x + silu_f(c0[4*g+1] + b4.y) * w4.y
                + silu_f(c0[4*g+2] + b4.z) * w4.z + silu_f(c0[4*g+3] + b4.w) * w4.w;
            s1 += silu_f(c1[4*g+0] + b4.x) * w4.x + silu_f(c1[4*g+1] + b4.y) * w4.y
                + silu_f(c1[4*g+2] + b4.z) * w4.z + silu_f(c1[4*g+3] + b4.w) * w4.w;
        }
        s0 += __shfl_xor(s0, 32);
        s1 += __shfl_xor(s1, 32);
        if (khalf == 0) {
            atomicAdd(&s_wgt[m0a + l31], s0);
            atomicAdd(&s_wgt[m0b + l31], s1);
        }
    }
    __syncthreads();                                           // B10

    // ---- per-edge coord vector into LDS ----
    if (tid < EMT) {
        int e = tid;
        float wgt = s_wgt[e] + cb2[0];
        int s = s_src[e], d = s_dst[e];
        float dx = coords[s * 3 + 0] - coords[d * 3 + 0];
        float dy = coords[s * 3 + 1] - coords[d * 3 + 1];
        float dz = coords[s * 3 + 2] - coords[d * 3 + 2];
        float inv = __fdividef(wgt, sqrtf(dx * dx + dy * dy + dz * dz) + EPS);
        s_cv[e][0] = dx * inv; s_cv[e][1] = dy * inv; s_cv[e][2] = dz * inv;
    }
    __syncthreads();                                           // B11

    // ---- message segment-reduction: thread = (column quad, 16-row stripe) ----
    {
        int q  = tid & 31;        // cols q*4 .. q*4+3
        int st = tid >> 5;        // rows st*16 .. st*16+15
        int cc = q * 4;
        float a0 = 0.f, a1 = 0.f, a2 = 0.f, a3 = 0.f;
        #pragma unroll
        for (int r = 0; r < 16; ++r) {
            int e = st * 16 + r;
            bf16x4 m = *(const bf16x4*)&R[e * RSTRIDE + cc];
            a0 += bf2f(m[0]); a1 += bf2f(m[1]); a2 += bf2f(m[2]); a3 += bf2f(m[3]);
            if (s_segend[e]) {
                float* ap = &aggr_nodes[(size_t)s_dst[e] * D + cc];
                unsafeAtomicAdd(ap + 0, a0); unsafeAtomicAdd(ap + 1, a1);
                unsafeAtomicAdd(ap + 2, a2); unsafeAtomicAdd(ap + 3, a3);
                a0 = a1 = a2 = a3 = 0.f;
            }
        }
        int elast = st * 16 + 15;
        if (!s_segend[elast]) {
            float* ap = &aggr_nodes[(size_t)s_dst[elast] * D + cc];
            unsafeAtomicAdd(ap + 0, a0); unsafeAtomicAdd(ap + 1, a1);
            unsafeAtomicAdd(ap + 2, a2); unsafeAtomicAdd(ap + 3, a3);
        }
    }

    // ---- coord segment-reduction: segment heads walk their run ----
    if (tid < EMT) {
        int e = tid;
        bool head = (e == 0) || (s_dst[e] != s_dst[e - 1]);
        if (head) {
            float sx = 0.f, sy = 0.f, sz = 0.f;
            int j = e;
            do {
                sx += s_cv[j][0]; sy += s_cv[j][1]; sz += s_cv[j][2];
                ++j;
            } while (j < EMT && s_dst[j] == s_dst[e]);
            int d = s_dst[e];
            unsafeAtomicAdd(&out_coords[d * 3 + 0], sx);
            unsafeAtomicAdd(&out_coords[d * 3 + 1], sy);
            unsafeAtomicAdd(&out_coords[d * 3 + 2], sz);
        }
    }
}

// ---------------------------------------------------------------------------
// node kernel (MFMA, swapped operands): 64 nodes/block; in-place aggr -> out.
// ---------------------------------------------------------------------------
__global__ __launch_bounds__(256, 4)
void node_kernel(const float* __restrict__ node_feat,
                 const short* __restrict__ nfbf,
                 float* nodes_io,
                 const float* __restrict__ nb1, const float* __restrict__ nb2,
                 const short* __restrict__ wsf) {
    __shared__ __align__(16) short lds[MT * NSTRIDE];
    __shared__ __align__(16) float s_nb1[D], s_nb2[D];
    const int tid = threadIdx.x;
    const int N0 = blockIdx.x * MT;

    if (tid < 128) { s_nb1[tid] = nb1[tid]; s_nb2[tid] = nb2[tid]; }
    {
        int i = tid >> 2, p = tid & 3;
        int nid = N0 + i; if (nid > N_NODES - 1) nid = N_NODES - 1;
        const short* frow = nfbf + (size_t)nid * D;
        short* drow = &lds[i * NSTRIDE];
        #pragma unroll
        for (int c = 0; c < 4; ++c)
            *(bf16x8*)&drow[c * 32 + p * 8] = *(const bf16x8*)&frow[c * 32 + p * 8];
        const float* arow = nodes_io + (size_t)nid * D + p * 32;
        #pragma unroll
        for (int c = 0; c < 4; ++c) {
            float4 f0 = *(const float4*)&arow[c * 8];
            float4 f1 = *(const float4*)&arow[c * 8 + 4];
            bf16x8 pk;
            pk[0]=f2bf(f0.x); pk[1]=f2bf(f0.y); pk[2]=f2bf(f0.z); pk[3]=f2bf(f0.w);
            pk[4]=f2bf(f1.x); pk[5]=f2bf(f1.y); pk[6]=f2bf(f1.z); pk[7]=f2bf(f1.w);
            *(bf16x8*)&drow[128 + p * 32 + c * 8] = pk;
        }
    }
    __syncthreads();

    const int lane  = tid & 63;
    const int wv    = tid >> 6;
    const int m0    = (wv >> 1) * 32;
    const int n0q   = wv & 1;
    const int l31   = lane & 31;
    const int khalf = lane >> 5;

    const bf16x8* W1 = (const bf16x8*)(wsf + NW1_OFF);
    const bf16x8* W2 = (const bf16x8*)(wsf + NW2_OFF);

    {
        f32x16 acc0, acc1;
        #pragma unroll
        for (int r = 0; r < 16; ++r) { acc0[r] = 0.f; acc1[r] = 0.f; }
        #pragma unroll
        for (int kc = 0; kc < 16; ++kc) {
            bf16x8 a  = *(const bf16x8*)&lds[(m0 + l31) * NSTRIDE + kc * 16 + khalf * 8];
            bf16x8 b0 = W1[(kc * 4 + n0q * 2 + 0) * 64 + lane];
            bf16x8 b1 = W1[(kc * 4 + n0q * 2 + 1) * 64 + lane];
            acc0 = __builtin_amdgcn_mfma_f32_32x32x16_bf16(b0, a, acc0, 0, 0, 0);
            acc1 = __builtin_amdgcn_mfma_f32_32x32x16_bf16(b1, a, acc1, 0, 0, 0);
        }
        __syncthreads();
        int nrow = m0 + l31;
        #pragma unroll
        for (int nt = 0; nt < 2; ++nt) {
            f32x16 A = nt ? acc1 : acc0;
            int base = n0q * 64 + nt * 32 + 4 * khalf;
            #pragma unroll
            for (int g = 0; g < 4; ++g) {
                int n = base + 8 * g;
                float4 b4 = *(const float4*)&s_nb1[n];
                uint2 dd;
                dd.x = cvt_pk_bf16(silu_f(A[4*g+0] + b4.x), silu_f(A[4*g+1] + b4.y));
                dd.y = cvt_pk_bf16(silu_f(A[4*g+2] + b4.z), silu_f(A[4*g+3] + b4.w));
                *(uint2*)&lds[nrow * HSTRIDE + n] = dd;
            }
        }
    }
    __syncthreads();

    {
        f32x16 acc0, acc1;
        #pragma unroll
        for (int r = 0; r < 16; ++r) { acc0[r] = 0.f; acc1[r] = 0.f; }
        #pragma unroll
        for (int kc = 0; kc < 8; ++kc) {
            bf16x8 a  = *(const bf16x8*)&lds[(m0 + l31) * HSTRIDE + kc * 16 + khalf * 8];
            bf16x8 b0 = W2[(kc * 4 + n0q * 2 + 0) * 64 + lane];
            bf16x8 b1 = W2[(kc * 4 + n0q * 2 + 1) * 64 + lane];
            acc0 = __builtin_amdgcn_mfma_f32_32x32x16_bf16(b0, a, acc0, 0, 0, 0);
            acc1 = __builtin_amdgcn_mfma_f32_32x32x16_bf16(b1, a, acc1, 0, 0, 0);
        }
        int nid = N0 + m0 + l31;
        if (nid < N_NODES) {
            #pragma unroll
            for (int nt = 0; nt < 2; ++nt) {
                f32x16 A = nt ? acc1 : acc0;
                int base = n0q * 64 + nt * 32 + 4 * khalf;
                #pragma unroll
                for (int g = 0; g < 4; ++g) {
                    int n = base + 8 * g;
                    float4 b4  = *(const float4*)&s_nb2[n];
                    float4 rsd = *(const float4*)&node_feat[(size_t)nid * D + n];
                    float4 o;
                    o.x = A[4*g+0] + b4.x + rsd.x;
                    o.y = A[4*g+1] + b4.y + rsd.y;
                    o.z = A[4*g+2] + b4.z + rsd.z;
                    o.w = A[4*g+3] + b4.w + rsd.w;
                    *(float4*)&nodes_io[(size_t)nid * D + n] = o;
                }
            }
        }
    }
}

extern "C" void kernel_launch(void* const* d_in, const int* in_sizes, int n_in,
                              void* d_out, int out_size, void* d_ws, size_t ws_size,
                              hipStream_t stream) {
    const float* node_feat  = (const float*)d_in[0];
    const int*   edge_index = (const int*)d_in[1];
    const float* edge_attr  = (const float*)d_in[2];
    const float* coords     = (const float*)d_in[3];
    const float* eW1 = (const float*)d_in[4];
    const float* eb1 = (const float*)d_in[5];
    const float* eW2 = (const float*)d_in[6];
    const float* eb2 = (const float*)d_in[7];
    const float* nW1 = (const float*)d_in[8];
    const float* nb1 = (const float*)d_in[9];
    const float* nW2 = (const float*)d_in[10];
    const float* nb2 = (const float*)d_in[11];
    const float* cW1 = (const float*)d_in[12];
    const float* cb1 = (const float*)d_in[13];
    const float* cW2 = (const float*)d_in[14];
    const float* cb2 = (const float*)d_in[15];

    float* nodes_io   = (float*)d_out;                 // aggr, then node output
    float* out_coords = nodes_io + (size_t)N_NODES * D;
    short* wsf    = (short*)d_ws;
    short* nfbf   = wsf + NFBF_OFF;
    int*   cnt    = (int*)(wsf + CSR_OFF);
    int*   cursor = cnt + N_NODES;
    int*   perm   = cursor + N_NODES;

    prep_kernel<<<256, 256, 0, stream>>>(
        eW1, eW2, cW1, nW1, nW2, node_feat, coords,
        wsf, nfbf, cnt, nodes_io, out_coords);
    hist_kernel<<<N_EDGES / 256, 256, 0, stream>>>(edge_index, cnt);
    scan_kernel<<<1, SCAN_T, 0, stream>>>(cnt, cursor);
    scatter_kernel<<<N_EDGES / 256, 256, 0, stream>>>(edge_index, cursor, perm);
    edge_kernel<<<N_EDGES / EMT, 256, 0, stream>>>(
        nfbf, edge_index, perm, edge_attr, coords,
        eb1, eb2, cb1, cW2, cb2, wsf, nodes_io, out_coords);
    node_kernel<<<(N_NODES + MT - 1) / MT, 256, 0, stream>>>(
        node_feat, nfbf, nodes_io, nb1, nb2, wsf);
}